// Round 2
// baseline (375.607 us; speedup 1.0000x reference)
//
#include <hip/hip_runtime.h>
#include <hip/hip_bf16.h>

// ---------------------------------------------------------------------------
// MultiheadAttention: x[2,2048,1024] fp32 -> out[2,2048,1024] fp32. H=16, D=64.
// Round 14: attn is now LDS-FREE. rd1 post-mortem showed the LDS pipe ~75%
// busy (9216 ds_b128/CU x ~10cyc vs 135K total cyc) with 8x redundant reads
// of L2-resident K/V. New attn: each wave loads its own K/V MFMA fragments
// directly from global (L1/L2-served), sigma key-permutation folded into the
// global address (as rd1 staging), register double-buffer one 32-key tile
// ahead, NO barriers, 256-thr blocks (4 waves x 16 q).
//   0) cast2   : x -> xb bf16, wqkv -> wqkvb bf16 into d_out scratch.
//   1) qkv_gemm: 128x128 bf16 MFMA GEMM, global_load_lds(16B) DMA staging,
//                double-buffered. -> Q (x log2e/8), K, Vt.
//   2) attn    : transposed flash attention (unshifted base-2 softmax,
//                in-register P transpose), direct-global fragments.
//   2b) cast wo -> wob bf16 (Q slot, dead after attn).
//   3) out_gemm: 64x128 tile, DMA double-buffered like qkv.
// ws (32 MiB): [Q 8 | K 8 | Vt 8 | AO 8]; wob overlays Q after attn.
// MFMA 16x16x32 bf16 layouts (m89/m91 verified):
//   A-frag: lane holds A[m=lane&15][k=(lane>>4)*8+j]
//   B-frag: lane holds B[k=(lane>>4)*8+j][n=lane&15]
//   C/D   : lane holds D[row=(lane>>4)*4+i][col=lane&15]
// sigma: QK^T A-row r<16 -> key (r>>2)*8+(r&3); row 16+r -> +4. So lane
// (quad,i) holds S[key=quad*8+i] (sA) and S[key=quad*8+4+i] (sB), and the
// packed bP[j] = P[key=quad*8+j] matches PV's B-frag k-mapping exactly.
// ---------------------------------------------------------------------------

typedef __attribute__((ext_vector_type(8))) short bf16x8;
typedef __attribute__((ext_vector_type(4))) short bf16x4;
typedef __attribute__((ext_vector_type(4))) float f32x4;

#define MFMA16(a, b, c) __builtin_amdgcn_mfma_f32_16x16x32_bf16((a), (b), (c), 0, 0, 0)

#if __has_builtin(__builtin_amdgcn_exp2f)
#define EXP2F(x) __builtin_amdgcn_exp2f(x)
#else
#define EXP2F(x) exp2f(x)
#endif

static __device__ __forceinline__ unsigned short f2bf_bits(float v) {
    __hip_bfloat16 h = __float2bfloat16(v);
    return *reinterpret_cast<unsigned short*>(&h);
}

static __device__ __forceinline__ bf16x8 cvt8(const float* p) {
    const f32x4 a = reinterpret_cast<const f32x4*>(p)[0];
    const f32x4 b = reinterpret_cast<const f32x4*>(p)[1];
    bf16x8 r;
    r[0] = (short)f2bf_bits(a[0]); r[1] = (short)f2bf_bits(a[1]);
    r[2] = (short)f2bf_bits(a[2]); r[3] = (short)f2bf_bits(a[3]);
    r[4] = (short)f2bf_bits(b[0]); r[5] = (short)f2bf_bits(b[1]);
    r[6] = (short)f2bf_bits(b[2]); r[7] = (short)f2bf_bits(b[3]);
    return r;
}

__device__ __forceinline__ bf16x8 ldg8(const __hip_bfloat16* p) {
    return *reinterpret_cast<const bf16x8*>(p);
}

// direct HBM -> LDS DMA, 16 B per lane; lds base must be wave-uniform
__device__ __forceinline__ void load16_lds(const __hip_bfloat16* g, unsigned short* l) {
    __builtin_amdgcn_global_load_lds(
        (const __attribute__((address_space(1))) void*)g,
        (__attribute__((address_space(3))) void*)l, 16, 0, 0);
}

// ---------------------------------------------------------------------------
// Kernel 0: merged cast. blocks [0,512) -> x (4M elems), [512,896) -> wqkv (3M).
// ---------------------------------------------------------------------------
__global__ __launch_bounds__(256)
void cast2_f32_bf16(const float* __restrict__ x, __hip_bfloat16* __restrict__ xb,
                    const float* __restrict__ w, __hip_bfloat16* __restrict__ wb) {
    const int bid = blockIdx.x;
    const float* src = (bid < 512) ? x : w;
    __hip_bfloat16* dst = (bid < 512) ? xb : wb;
    const int rb = (bid < 512) ? bid : (bid - 512);
    const size_t base = (size_t)rb * 8192 + (size_t)threadIdx.x * 32;
#pragma unroll
    for (int i = 0; i < 4; ++i)
        *reinterpret_cast<bf16x8*>(dst + base + i * 8) = cvt8(src + base + i * 8);
}

__global__ __launch_bounds__(256)
void cast_f32_bf16(const float* __restrict__ src, __hip_bfloat16* __restrict__ dst) {
    const size_t base = ((size_t)blockIdx.x * 256 + threadIdx.x) * 32;
#pragma unroll
    for (int i = 0; i < 4; ++i)
        *reinterpret_cast<bf16x8*>(dst + base + i * 8) = cvt8(src + base + i * 8);
}

// ---------------------------------------------------------------------------
// Kernel 1: QKV projection, 128x128 tile, double-buffered DMA staging.
// Q pre-scaled by (1/8)*log2(e).
// ---------------------------------------------------------------------------
__global__ __launch_bounds__(256)
void qkv_gemm(const __hip_bfloat16* __restrict__ xb,
              const __hip_bfloat16* __restrict__ wb,
              const float* __restrict__ bqkv,
              __hip_bfloat16* __restrict__ Q,
              __hip_bfloat16* __restrict__ K,
              __hip_bfloat16* __restrict__ Vt) {
    __shared__ unsigned short As[2][128 * 32];   // unpadded (DMA landing rule)
    __shared__ unsigned short Bs[2][128 * 32];

    const int tid  = threadIdx.x;
    const int lane = tid & 63;
    const int wv   = tid >> 6;
    const int quad = lane >> 4;
    const int l16  = lane & 15;
    const int wm   = wv >> 1;
    const int wn   = wv & 1;

    const int bid = blockIdx.x;          // 0..767
    const int xcd = bid & 7;
    const int r   = bid >> 3;            // 0..95
    const int m0  = (r / 3) * 128;
    const int n0  = (xcd * 3 + (r % 3)) * 128;

    // DMA source: lane l -> row base+(l>>2), 16B chunk (l&3)
    const __hip_bfloat16* agl = xb + (size_t)(m0 + wv * 32 + (lane >> 2)) * 1024 + (lane & 3) * 8;
    const __hip_bfloat16* bgl = wb + (size_t)(n0 + wv * 32 + (lane >> 2)) * 1024 + (lane & 3) * 8;

    f32x4 zv = {0.f, 0.f, 0.f, 0.f};
    f32x4 acc[4][4];
#pragma unroll
    for (int ii = 0; ii < 4; ++ii)
#pragma unroll
        for (int jj = 0; jj < 4; ++jj) acc[ii][jj] = zv;

    // prologue: DMA tile 0 into buffer 0
    load16_lds(agl, &As[0][(wv * 32) * 32]);
    load16_lds(agl + 16 * 1024, &As[0][(wv * 32 + 16) * 32]);
    load16_lds(bgl, &Bs[0][(wv * 32) * 32]);
    load16_lds(bgl + 16 * 1024, &Bs[0][(wv * 32 + 16) * 32]);
    __syncthreads();

    for (int k0 = 0; k0 < 1024; k0 += 32) {
        const int p = (k0 >> 5) & 1;
        // prefetch next tile into the other buffer BEFORE compute
        if (k0 + 32 < 1024) {
            const int q = p ^ 1;
            load16_lds(agl + k0 + 32, &As[q][(wv * 32) * 32]);
            load16_lds(agl + 16 * 1024 + k0 + 32, &As[q][(wv * 32 + 16) * 32]);
            load16_lds(bgl + k0 + 32, &Bs[q][(wv * 32) * 32]);
            load16_lds(bgl + 16 * 1024 + k0 + 32, &Bs[q][(wv * 32 + 16) * 32]);
        }
        bf16x8 af[4], bf[4];
#pragma unroll
        for (int ii = 0; ii < 4; ++ii)
            af[ii] = *reinterpret_cast<const bf16x8*>(
                &As[p][(wm * 64 + ii * 16 + l16) * 32 + quad * 8]);
#pragma unroll
        for (int jj = 0; jj < 4; ++jj)
            bf[jj] = *reinterpret_cast<const bf16x8*>(
                &Bs[p][(wn * 64 + jj * 16 + l16) * 32 + quad * 8]);
#pragma unroll
        for (int ii = 0; ii < 4; ++ii)
#pragma unroll
            for (int jj = 0; jj < 4; ++jj)
                acc[ii][jj] = MFMA16(af[ii], bf[jj], acc[ii][jj]);
        __syncthreads();   // drains DMA (mostly overlapped) + guards reuse
    }

    const float QSCALE = 0.18033688011f;   // 0.125 * log2(e)

#pragma unroll
    for (int jj = 0; jj < 4; ++jj) {
        const int n = n0 + wn * 64 + jj * 16 + l16;
        const float bias = bqkv[n];
        const int h = n / 192;
        const int r2 = n - h * 192;
        const int t = r2 >> 6;              // 0=Q 1=K 2=V
        const int d = r2 & 63;
#pragma unroll
        for (int ii = 0; ii < 4; ++ii) {
            const int mb = m0 + wm * 64 + ii * 16 + quad * 4;  // 4 consecutive m
            const int b = mb >> 11;
            const int s0 = mb & 2047;
            const int bh = b * 16 + h;
            if (t == 2) {
                bf16x4 pk;
#pragma unroll
                for (int i = 0; i < 4; ++i)
                    pk[i] = (short)f2bf_bits(acc[ii][jj][i] + bias);
                *reinterpret_cast<bf16x4*>(&Vt[((size_t)bh * 64 + d) * 2048 + s0]) = pk;
            } else {
#pragma unroll
                for (int i = 0; i < 4; ++i) {
                    const float v = acc[ii][jj][i] + bias;
                    if (t == 0)
                        Q[((size_t)bh * 2048 + s0 + i) * 64 + d] = __float2bfloat16(v * QSCALE);
                    else
                        K[((size_t)bh * 2048 + s0 + i) * 64 + d] = __float2bfloat16(v);
                }
            }
        }
    }
}

// ---------------------------------------------------------------------------
// Kernel 2: transposed flash attention, LDS-free direct-global fragments.
// 1024 blocks x 256 threads (4 waves x 16 q = 64 q/block). 32 keys/iter.
// Each wave loads its own K/V fragments from global (L1/L2-served; K+V of a
// bh = 512 KB, pinned to one XCD's L2 by the swizzle, shared by 32 blocks).
// Register double-buffer one tile ahead; NO LDS, NO barriers.
// ---------------------------------------------------------------------------
__global__ __launch_bounds__(256, 4)
void attn_kernel(const __hip_bfloat16* __restrict__ Q,
                 const __hip_bfloat16* __restrict__ K,
                 const __hip_bfloat16* __restrict__ Vt,
                 __hip_bfloat16* __restrict__ AO) {
    const int tid  = threadIdx.x;
    const int lane = tid & 63;
    const int wv   = tid >> 6;           // 0..3
    const int quad = lane >> 4;
    const int l16  = lane & 15;

    const int blk = blockIdx.x;          // 0..1023
    const int xcd = blk & 7;
    const int sub = blk >> 3;            // 0..127
    const int bh  = xcd * 4 + (sub & 3);
    const int qb  = sub >> 2;            // 0..31
    const int q0  = qb * 64 + wv * 16;
    const int b   = bh >> 4;
    const int h   = bh & 15;

    const __hip_bfloat16* Qp = Q  + (size_t)bh * 131072;   // [S,D]
    const __hip_bfloat16* Kp = K  + (size_t)bh * 131072;   // [S,D]
    const __hip_bfloat16* Vp = Vt + (size_t)bh * 131072;   // [D,S]

    const bf16x8 bQ0 = ldg8(Qp + (size_t)(q0 + l16) * 64 + quad * 8);
    const bf16x8 bQ1 = ldg8(Qp + (size_t)(q0 + l16) * 64 + 32 + quad * 8);

    // sigma-permuted K row for this lane (A-part); B-part is +4 keys.
    const int key_a = (l16 >> 2) * 8 + (l16 & 3);
    const __hip_bfloat16* ka = Kp + (size_t)key_a * 64 + quad * 8;
    const __hip_bfloat16* kb = ka + 4 * 64;
    const __hip_bfloat16* va = Vp + (size_t)l16 * 2048 + quad * 8;

    const f32x4 zv = {0.f, 0.f, 0.f, 0.f};
    f32x4 Of0 = zv, Of1 = zv, Of2 = zv, Of3 = zv;
    float li = 0.f;

    struct Frags { bf16x8 kA0, kA1, kB0, kB1, v0, v1, v2, v3; };

    auto LOAD = [&](int kt, Frags& F) {
        const size_t ko = (size_t)kt * 2048;   // 32 keys * 64 d
        const size_t vo = (size_t)kt * 32;     // 32 keys along V^T rows
        F.kA0 = ldg8(ka + ko);
        F.kA1 = ldg8(ka + ko + 32);
        F.kB0 = ldg8(kb + ko);
        F.kB1 = ldg8(kb + ko + 32);
        F.v0  = ldg8(va + vo);
        F.v1  = ldg8(va + vo + (size_t)16 * 2048);
        F.v2  = ldg8(va + vo + (size_t)32 * 2048);
        F.v3  = ldg8(va + vo + (size_t)48 * 2048);
    };

    auto COMPUTE = [&](const Frags& F) {
        f32x4 sA = zv, sB = zv;
        sA = MFMA16(F.kA0, bQ0, sA);
        sA = MFMA16(F.kA1, bQ1, sA);
        sB = MFMA16(F.kB0, bQ0, sB);
        sB = MFMA16(F.kB1, bQ1, sB);

        float pA[4], pB[4];
#pragma unroll
        for (int i = 0; i < 4; ++i) {
            pA[i] = EXP2F(sA[i]);
            pB[i] = EXP2F(sB[i]);
        }
        li += ((pA[0] + pA[1]) + (pA[2] + pA[3]))
            + ((pB[0] + pB[1]) + (pB[2] + pB[3]));

        bf16x8 bP;
        bP[0] = (short)f2bf_bits(pA[0]); bP[1] = (short)f2bf_bits(pA[1]);
        bP[2] = (short)f2bf_bits(pA[2]); bP[3] = (short)f2bf_bits(pA[3]);
        bP[4] = (short)f2bf_bits(pB[0]); bP[5] = (short)f2bf_bits(pB[1]);
        bP[6] = (short)f2bf_bits(pB[2]); bP[7] = (short)f2bf_bits(pB[3]);

        Of0 = MFMA16(F.v0, bP, Of0);
        Of1 = MFMA16(F.v1, bP, Of1);
        Of2 = MFMA16(F.v2, bP, Of2);
        Of3 = MFMA16(F.v3, bP, Of3);
    };

    Frags fa, fb;
    LOAD(0, fa);
    for (int kt = 0; kt < 64; kt += 2) {
        LOAD(kt + 1, fb);                 // kt <= 62 -> kt+1 <= 63, in range
        COMPUTE(fa);
        if (kt + 2 < 64) LOAD(kt + 2, fa);
        COMPUTE(fb);
    }

    li += __shfl_xor(li, 16);
    li += __shfl_xor(li, 32);

    {
        const float linv = 1.f / li;
        const int s = q0 + l16;
        __hip_bfloat16* aop = AO + (((size_t)b * 2048 + s) * 16 + h) * 64;
        f32x4 Of[4] = {Of0, Of1, Of2, Of3};
#pragma unroll
        for (int jj = 0; jj < 4; ++jj) {
            bf16x4 pk;
#pragma unroll
            for (int i = 0; i < 4; ++i)
                pk[i] = (short)f2bf_bits(Of[jj][i] * linv);
            *reinterpret_cast<bf16x4*>(aop + jj * 16 + quad * 4) = pk;
        }
    }
}

// ---------------------------------------------------------------------------
// Kernel 3: output projection, 64(M)x128(N) tile, double-buffered DMA staging.
// 512 blocks = 2/CU. Waves 2x2: wave tile 32(M)x64(N).
// ---------------------------------------------------------------------------
__global__ __launch_bounds__(256)
void out_gemm(const __hip_bfloat16* __restrict__ A,
              const __hip_bfloat16* __restrict__ wob,
              const float* __restrict__ bo,
              float* __restrict__ out) {
    __shared__ unsigned short As[2][64 * 32];    // unpadded
    __shared__ unsigned short Bs[2][128 * 32];

    const int tid  = threadIdx.x;
    const int lane = tid & 63;
    const int wv   = tid >> 6;
    const int quad = lane >> 4;
    const int l16  = lane & 15;
    const int wm   = wv >> 1;
    const int wn   = wv & 1;

    const int bid = blockIdx.x;          // 0..511
    const int m0  = (bid >> 3) * 64;
    const int n0  = (bid & 7) * 128;

    const __hip_bfloat16* agl = A   + (size_t)(m0 + wv * 16 + (lane >> 2)) * 1024 + (lane & 3) * 8;
    const __hip_bfloat16* bgl = wob + (size_t)(n0 + wv * 32 + (lane >> 2)) * 1024 + (lane & 3) * 8;

    f32x4 zv = {0.f, 0.f, 0.f, 0.f};
    f32x4 acc[2][4];
#pragma unroll
    for (int ii = 0; ii < 2; ++ii)
#pragma unroll
        for (int jj = 0; jj < 4; ++jj) acc[ii][jj] = zv;

    load16_lds(agl, &As[0][(wv * 16) * 32]);
    load16_lds(bgl, &Bs[0][(wv * 32) * 32]);
    load16_lds(bgl + 16 * 1024, &Bs[0][(wv * 32 + 16) * 32]);
    __syncthreads();

    for (int k0 = 0; k0 < 1024; k0 += 32) {
        const int p = (k0 >> 5) & 1;
        if (k0 + 32 < 1024) {
            const int q = p ^ 1;
            load16_lds(agl + k0 + 32, &As[q][(wv * 16) * 32]);
            load16_lds(bgl + k0 + 32, &Bs[q][(wv * 32) * 32]);
            load16_lds(bgl + 16 * 1024 + k0 + 32, &Bs[q][(wv * 32 + 16) * 32]);
        }
        bf16x8 af[2], bf[4];
#pragma unroll
        for (int ii = 0; ii < 2; ++ii)
            af[ii] = *reinterpret_cast<const bf16x8*>(
                &As[p][(wm * 32 + ii * 16 + l16) * 32 + quad * 8]);
#pragma unroll
        for (int jj = 0; jj < 4; ++jj)
            bf[jj] = *reinterpret_cast<const bf16x8*>(
                &Bs[p][(wn * 64 + jj * 16 + l16) * 32 + quad * 8]);
#pragma unroll
        for (int ii = 0; ii < 2; ++ii)
#pragma unroll
            for (int jj = 0; jj < 4; ++jj)
                acc[ii][jj] = MFMA16(af[ii], bf[jj], acc[ii][jj]);
        __syncthreads();
    }

#pragma unroll
    for (int jj = 0; jj < 4; ++jj) {
        const int n = n0 + wn * 64 + jj * 16 + l16;
        const float bias = bo[n];
#pragma unroll
        for (int ii = 0; ii < 2; ++ii) {
#pragma unroll
            for (int i = 0; i < 4; ++i) {
                const int m = m0 + wm * 32 + ii * 16 + quad * 4 + i;
                out[(size_t)m * 1024 + n] = acc[ii][jj][i] + bias;
            }
        }
    }
}

// ---------------------------------------------------------------------------
extern "C" void kernel_launch(void* const* d_in, const int* in_sizes, int n_in,
                              void* d_out, int out_size, void* d_ws, size_t ws_size,
                              hipStream_t stream) {
    const float* x    = (const float*)d_in[0];
    const float* wqkv = (const float*)d_in[1];
    const float* bqkv = (const float*)d_in[2];
    const float* wo   = (const float*)d_in[3];
    const float* bo   = (const float*)d_in[4];
    float* out = (float*)d_out;

    __hip_bfloat16* ws = (__hip_bfloat16*)d_ws;
    __hip_bfloat16* Q   = ws;                      // [32,2048,64] (x log2e/8)
    __hip_bfloat16* K   = ws + (size_t)4194304;
    __hip_bfloat16* Vt  = ws + (size_t)8388608;
    __hip_bfloat16* AO  = ws + (size_t)12582912;
    __hip_bfloat16* wob = Q;                       // overlay after attn

    // d_out doubles as pre-pass scratch (dead until out_gemm rewrites it):
    __hip_bfloat16* xb     = (__hip_bfloat16*)d_out;            // 4M elems, 8 MB
    __hip_bfloat16* wqkvb  = xb + (size_t)4194304;              // 3M elems, 6 MB

    // 0) merged casts: x (512 blocks) + wqkv (384 blocks)
    cast2_f32_bf16<<<dim3(896), 256, 0, stream>>>(x, xb, wqkv, wqkvb);
    // 1) QKV projection: M=4096, N=3072, K=1024
    qkv_gemm<<<dim3(768), 256, 0, stream>>>(xb, wqkvb, bqkv, Q, K, Vt);
    // 2) attention: 32 bh x 32 q-blocks = 1024 blocks, 4 waves each, no LDS
    attn_kernel<<<dim3(1024), 256, 0, stream>>>(Q, K, Vt, AO);
    // 2b) wo fp32 -> bf16 into dead Q slot (1M elems)
    cast_f32_bf16<<<dim3(128), 256, 0, stream>>>(wo, wob);
    // 3) output projection: M=4096, N=1024, K=1024
    out_gemm<<<dim3(512), 256, 0, stream>>>(AO, wob, bo, out);
}

// Round 3
// 190.835 us; speedup vs baseline: 1.9682x; 1.9682x over previous
//
#include <hip/hip_runtime.h>
#include <hip/hip_bf16.h>

// ---------------------------------------------------------------------------
// MultiheadAttention: x[2,2048,1024] fp32 -> out[2,2048,1024] fp32. H=16, D=64.
// Round 15: rd2's LDS-free attn was L2-BW-bound (8.6 GB of 8x-redundant
// fragment gathers ~= 250us) -> reverted to rd1 LDS staging. New: FRAGMENT-
// MAJOR LDS layout. All waves read identical MFMA fragments, so the tile is
// stored in fragment order: slot (frag f, lane) at byte f*1024 + lane*16.
//   - reads:  base + lane*16 (+ imm frag offset) -> consecutive banks,
//             provably conflict-free (2 lanes/bank = free).
//   - writes: thread t -> byte t*16, linear, conflict-free.
//   - sigma key-permutation folded into the staging GLOBAL source address.
// rd1 measured 8.39M conflict-cycles (~25% of LDS-pipe time) from the 80B-row
// read pattern; this layout eliminates them. Compute math identical to rd1.
//   0) cast2   : x -> xb bf16, wqkv -> wqkvb bf16 into d_out scratch.
//   1) qkv_gemm: 128x128 bf16 MFMA GEMM, global_load_lds(16B) DMA staging,
//                double-buffered. -> Q (x log2e/8), K, Vt.
//   2) attn    : transposed flash attention (unshifted base-2 softmax,
//                in-register P transpose), fragment-major dbuf LDS,
//                1 barrier/iter, 512 blocks x 512 threads.
//   2b) cast wo -> wob bf16 (Q slot, dead after attn).
//   3) out_gemm: 64x128 tile, DMA double-buffered like qkv.
// ws (32 MiB): [Q 8 | K 8 | Vt 8 | AO 8]; wob overlays Q after attn.
// MFMA 16x16x32 bf16 layouts (m89/m91 verified):
//   A-frag: lane holds A[m=lane&15][k=(lane>>4)*8+j]
//   B-frag: lane holds B[k=(lane>>4)*8+j][n=lane&15]
//   C/D   : lane holds D[row=(lane>>4)*4+i][col=lane&15]
// sigma: QK^T A-row r<16 -> key (r>>2)*8+(r&3); row 16+r -> +4. Lane (quad,i)
// holds S[key=quad*8+i] (sA) and S[key=quad*8+4+i] (sB); packed bP[j] =
// P[key=quad*8+j] matches PV's B-frag k-mapping exactly.
// ---------------------------------------------------------------------------

typedef __attribute__((ext_vector_type(8))) short bf16x8;
typedef __attribute__((ext_vector_type(4))) short bf16x4;
typedef __attribute__((ext_vector_type(4))) float f32x4;

#define MFMA16(a, b, c) __builtin_amdgcn_mfma_f32_16x16x32_bf16((a), (b), (c), 0, 0, 0)

#if __has_builtin(__builtin_amdgcn_exp2f)
#define EXP2F(x) __builtin_amdgcn_exp2f(x)
#else
#define EXP2F(x) exp2f(x)
#endif

static __device__ __forceinline__ unsigned short f2bf_bits(float v) {
    __hip_bfloat16 h = __float2bfloat16(v);
    return *reinterpret_cast<unsigned short*>(&h);
}

static __device__ __forceinline__ bf16x8 cvt8(const float* p) {
    const f32x4 a = reinterpret_cast<const f32x4*>(p)[0];
    const f32x4 b = reinterpret_cast<const f32x4*>(p)[1];
    bf16x8 r;
    r[0] = (short)f2bf_bits(a[0]); r[1] = (short)f2bf_bits(a[1]);
    r[2] = (short)f2bf_bits(a[2]); r[3] = (short)f2bf_bits(a[3]);
    r[4] = (short)f2bf_bits(b[0]); r[5] = (short)f2bf_bits(b[1]);
    r[6] = (short)f2bf_bits(b[2]); r[7] = (short)f2bf_bits(b[3]);
    return r;
}

__device__ __forceinline__ bf16x8 ldg8(const __hip_bfloat16* p) {
    return *reinterpret_cast<const bf16x8*>(p);
}

// direct HBM -> LDS DMA, 16 B per lane; lds base must be wave-uniform
__device__ __forceinline__ void load16_lds(const __hip_bfloat16* g, unsigned short* l) {
    __builtin_amdgcn_global_load_lds(
        (const __attribute__((address_space(1))) void*)g,
        (__attribute__((address_space(3))) void*)l, 16, 0, 0);
}

// ---------------------------------------------------------------------------
// Kernel 0: merged cast. blocks [0,512) -> x (4M elems), [512,896) -> wqkv (3M).
// ---------------------------------------------------------------------------
__global__ __launch_bounds__(256)
void cast2_f32_bf16(const float* __restrict__ x, __hip_bfloat16* __restrict__ xb,
                    const float* __restrict__ w, __hip_bfloat16* __restrict__ wb) {
    const int bid = blockIdx.x;
    const float* src = (bid < 512) ? x : w;
    __hip_bfloat16* dst = (bid < 512) ? xb : wb;
    const int rb = (bid < 512) ? bid : (bid - 512);
    const size_t base = (size_t)rb * 8192 + (size_t)threadIdx.x * 32;
#pragma unroll
    for (int i = 0; i < 4; ++i)
        *reinterpret_cast<bf16x8*>(dst + base + i * 8) = cvt8(src + base + i * 8);
}

__global__ __launch_bounds__(256)
void cast_f32_bf16(const float* __restrict__ src, __hip_bfloat16* __restrict__ dst) {
    const size_t base = ((size_t)blockIdx.x * 256 + threadIdx.x) * 32;
#pragma unroll
    for (int i = 0; i < 4; ++i)
        *reinterpret_cast<bf16x8*>(dst + base + i * 8) = cvt8(src + base + i * 8);
}

// ---------------------------------------------------------------------------
// Kernel 1: QKV projection, 128x128 tile, double-buffered DMA staging.
// Q pre-scaled by (1/8)*log2(e).
// ---------------------------------------------------------------------------
__global__ __launch_bounds__(256)
void qkv_gemm(const __hip_bfloat16* __restrict__ xb,
              const __hip_bfloat16* __restrict__ wb,
              const float* __restrict__ bqkv,
              __hip_bfloat16* __restrict__ Q,
              __hip_bfloat16* __restrict__ K,
              __hip_bfloat16* __restrict__ Vt) {
    __shared__ unsigned short As[2][128 * 32];   // unpadded (DMA landing rule)
    __shared__ unsigned short Bs[2][128 * 32];

    const int tid  = threadIdx.x;
    const int lane = tid & 63;
    const int wv   = tid >> 6;
    const int quad = lane >> 4;
    const int l16  = lane & 15;
    const int wm   = wv >> 1;
    const int wn   = wv & 1;

    const int bid = blockIdx.x;          // 0..767
    const int xcd = bid & 7;
    const int r   = bid >> 3;            // 0..95
    const int m0  = (r / 3) * 128;
    const int n0  = (xcd * 3 + (r % 3)) * 128;

    // DMA source: lane l -> row base+(l>>2), 16B chunk (l&3)
    const __hip_bfloat16* agl = xb + (size_t)(m0 + wv * 32 + (lane >> 2)) * 1024 + (lane & 3) * 8;
    const __hip_bfloat16* bgl = wb + (size_t)(n0 + wv * 32 + (lane >> 2)) * 1024 + (lane & 3) * 8;

    f32x4 zv = {0.f, 0.f, 0.f, 0.f};
    f32x4 acc[4][4];
#pragma unroll
    for (int ii = 0; ii < 4; ++ii)
#pragma unroll
        for (int jj = 0; jj < 4; ++jj) acc[ii][jj] = zv;

    // prologue: DMA tile 0 into buffer 0
    load16_lds(agl, &As[0][(wv * 32) * 32]);
    load16_lds(agl + 16 * 1024, &As[0][(wv * 32 + 16) * 32]);
    load16_lds(bgl, &Bs[0][(wv * 32) * 32]);
    load16_lds(bgl + 16 * 1024, &Bs[0][(wv * 32 + 16) * 32]);
    __syncthreads();

    for (int k0 = 0; k0 < 1024; k0 += 32) {
        const int p = (k0 >> 5) & 1;
        // prefetch next tile into the other buffer BEFORE compute
        if (k0 + 32 < 1024) {
            const int q = p ^ 1;
            load16_lds(agl + k0 + 32, &As[q][(wv * 32) * 32]);
            load16_lds(agl + 16 * 1024 + k0 + 32, &As[q][(wv * 32 + 16) * 32]);
            load16_lds(bgl + k0 + 32, &Bs[q][(wv * 32) * 32]);
            load16_lds(bgl + 16 * 1024 + k0 + 32, &Bs[q][(wv * 32 + 16) * 32]);
        }
        bf16x8 af[4], bf[4];
#pragma unroll
        for (int ii = 0; ii < 4; ++ii)
            af[ii] = *reinterpret_cast<const bf16x8*>(
                &As[p][(wm * 64 + ii * 16 + l16) * 32 + quad * 8]);
#pragma unroll
        for (int jj = 0; jj < 4; ++jj)
            bf[jj] = *reinterpret_cast<const bf16x8*>(
                &Bs[p][(wn * 64 + jj * 16 + l16) * 32 + quad * 8]);
#pragma unroll
        for (int ii = 0; ii < 4; ++ii)
#pragma unroll
            for (int jj = 0; jj < 4; ++jj)
                acc[ii][jj] = MFMA16(af[ii], bf[jj], acc[ii][jj]);
        __syncthreads();   // drains DMA (mostly overlapped) + guards reuse
    }

    const float QSCALE = 0.18033688011f;   // 0.125 * log2(e)

#pragma unroll
    for (int jj = 0; jj < 4; ++jj) {
        const int n = n0 + wn * 64 + jj * 16 + l16;
        const float bias = bqkv[n];
        const int h = n / 192;
        const int r2 = n - h * 192;
        const int t = r2 >> 6;              // 0=Q 1=K 2=V
        const int d = r2 & 63;
#pragma unroll
        for (int ii = 0; ii < 4; ++ii) {
            const int mb = m0 + wm * 64 + ii * 16 + quad * 4;  // 4 consecutive m
            const int b = mb >> 11;
            const int s0 = mb & 2047;
            const int bh = b * 16 + h;
            if (t == 2) {
                bf16x4 pk;
#pragma unroll
                for (int i = 0; i < 4; ++i)
                    pk[i] = (short)f2bf_bits(acc[ii][jj][i] + bias);
                *reinterpret_cast<bf16x4*>(&Vt[((size_t)bh * 64 + d) * 2048 + s0]) = pk;
            } else {
#pragma unroll
                for (int i = 0; i < 4; ++i) {
                    const float v = acc[ii][jj][i] + bias;
                    if (t == 0)
                        Q[((size_t)bh * 2048 + s0 + i) * 64 + d] = __float2bfloat16(v * QSCALE);
                    else
                        K[((size_t)bh * 2048 + s0 + i) * 64 + d] = __float2bfloat16(v);
                }
            }
        }
    }
}

// ---------------------------------------------------------------------------
// Kernel 2: transposed flash attention, fragment-major LDS.
// 512 blocks x 512 threads (8 waves x 16 q = 128 q/block). 32 keys/iter.
// LDS tile = 8 fragments x 64 lanes x 16B = 8KB/buffer, double-buffered.
//   frag 0..3 : K A-frags (A0: sigma-keys d[0,32); A1: d[32,64);
//                          B0: sigma-keys+4 d[0,32); B1: d[32,64))
//   frag 4..7 : V^T rows [jj*16+l16], key chunk quad*8.
// Staging: wave f stages fragment f (thread t -> LDS byte t*16, linear).
// Reads: base + lane*16 + imm frag offset -> conflict-free by construction.
// ---------------------------------------------------------------------------
__global__ __launch_bounds__(512, 4)
void attn_kernel(const __hip_bfloat16* __restrict__ Q,
                 const __hip_bfloat16* __restrict__ K,
                 const __hip_bfloat16* __restrict__ Vt,
                 __hip_bfloat16* __restrict__ AO) {
    __shared__ unsigned short SB[2][4096];   // 2 x 8KB, fragment-major

    const int tid  = threadIdx.x;
    const int lane = tid & 63;
    const int wv   = tid >> 6;           // 0..7 == fragment this wave stages
    const int quad = lane >> 4;
    const int l16  = lane & 15;

    const int blk = blockIdx.x;          // 0..511
    const int xcd = blk & 7;
    const int sub = blk >> 3;            // 0..63
    const int bh  = xcd * 4 + (sub & 3);
    const int qb  = sub >> 2;            // 0..15
    const int q0  = qb * 128 + wv * 16;
    const int b   = bh >> 4;
    const int h   = bh & 15;

    const __hip_bfloat16* Qp = Q  + (size_t)bh * 131072;   // [S,D]
    const __hip_bfloat16* Kp = K  + (size_t)bh * 131072;   // [S,D]
    const __hip_bfloat16* Vp = Vt + (size_t)bh * 131072;   // [D,S]

    bf16x8 bQ[2];
#pragma unroll
    for (int dh = 0; dh < 2; ++dh)
        bQ[dh] = ldg8(Qp + (size_t)(q0 + l16) * 64 + dh * 32 + quad * 8);

    // --- staging: wave wv stages fragment wv; LDS dst = byte tid*16 (linear).
    // Global source reproduces exactly what compute-lane `lane` expects:
    //   f<4 : K[key = (l16>>2)*8+(l16&3) + (f>=2 ? 4:0)][d = (f&1)*32+quad*8]
    //   f>=4: V^T[(f-4)*16 + l16][key0 + quad*8]
    const __hip_bfloat16* sgp;
    size_t sstep;
    if (wv < 4) {
        const int keyg = (l16 >> 2) * 8 + (l16 & 3) + ((wv >> 1) << 2);
        const int d0   = (wv & 1) * 32 + quad * 8;
        sgp   = Kp + (size_t)keyg * 64 + d0;
        sstep = 32 * 64;
    } else {
        sgp   = Vp + (size_t)((wv - 4) * 16 + l16) * 2048 + quad * 8;
        sstep = 32;
    }
    unsigned short* s0 = &SB[0][tid * 8];
    unsigned short* s1 = &SB[1][tid * 8];

    f32x4 zv = {0.f, 0.f, 0.f, 0.f};
    f32x4 Of[4];
#pragma unroll
    for (int jj = 0; jj < 4; ++jj) Of[jj] = zv;
    float li = 0.f;

    // prologue: tile 0 -> buf 0; prefetch tile 1 into reg
    bf16x8 g = ldg8(sgp);
    *reinterpret_cast<bf16x8*>(s0) = g;
    g = ldg8(sgp + sstep);
    __syncthreads();

    for (int kt = 0; kt < 64; ++kt) {
        const int p = kt & 1;
        // publish tile kt+1 (in reg) to the other buffer, then prefetch kt+2
        if (kt < 63)
            *reinterpret_cast<bf16x8*>(p ? s0 : s1) = g;
        if (kt < 62)
            g = ldg8(sgp + (size_t)(kt + 2) * sstep);

        const unsigned short* base = &SB[p][lane * 8];
        const bf16x8 aKA0 = *reinterpret_cast<const bf16x8*>(base + 0 * 512);
        const bf16x8 aKA1 = *reinterpret_cast<const bf16x8*>(base + 1 * 512);
        const bf16x8 aKB0 = *reinterpret_cast<const bf16x8*>(base + 2 * 512);
        const bf16x8 aKB1 = *reinterpret_cast<const bf16x8*>(base + 3 * 512);
        bf16x8 aV[4];
#pragma unroll
        for (int jj = 0; jj < 4; ++jj)
            aV[jj] = *reinterpret_cast<const bf16x8*>(base + (4 + jj) * 512);

        f32x4 sA = zv, sB = zv;
        sA = MFMA16(aKA0, bQ[0], sA);
        sA = MFMA16(aKA1, bQ[1], sA);
        sB = MFMA16(aKB0, bQ[0], sB);
        sB = MFMA16(aKB1, bQ[1], sB);

        float pA[4], pB[4];
#pragma unroll
        for (int i = 0; i < 4; ++i) {
            pA[i] = EXP2F(sA[i]);
            pB[i] = EXP2F(sB[i]);
        }
        li += ((pA[0] + pA[1]) + (pA[2] + pA[3]))
            + ((pB[0] + pB[1]) + (pB[2] + pB[3]));

        bf16x8 bP;
        bP[0] = (short)f2bf_bits(pA[0]); bP[1] = (short)f2bf_bits(pA[1]);
        bP[2] = (short)f2bf_bits(pA[2]); bP[3] = (short)f2bf_bits(pA[3]);
        bP[4] = (short)f2bf_bits(pB[0]); bP[5] = (short)f2bf_bits(pB[1]);
        bP[6] = (short)f2bf_bits(pB[2]); bP[7] = (short)f2bf_bits(pB[3]);

#pragma unroll
        for (int jj = 0; jj < 4; ++jj)
            Of[jj] = MFMA16(aV[jj], bP, Of[jj]);

        __syncthreads();   // single barrier: publishes buf[p^1], guards buf[p]
    }

    li += __shfl_xor(li, 16);
    li += __shfl_xor(li, 32);

    {
        const float linv = 1.f / li;
        const int s = q0 + l16;
        __hip_bfloat16* aop = AO + (((size_t)b * 2048 + s) * 16 + h) * 64;
#pragma unroll
        for (int jj = 0; jj < 4; ++jj) {
            bf16x4 pk;
#pragma unroll
            for (int i = 0; i < 4; ++i)
                pk[i] = (short)f2bf_bits(Of[jj][i] * linv);
            *reinterpret_cast<bf16x4*>(aop + jj * 16 + quad * 4) = pk;
        }
    }
}

// ---------------------------------------------------------------------------
// Kernel 3: output projection, 64(M)x128(N) tile, double-buffered DMA staging.
// 512 blocks = 2/CU. Waves 2x2: wave tile 32(M)x64(N).
// ---------------------------------------------------------------------------
__global__ __launch_bounds__(256)
void out_gemm(const __hip_bfloat16* __restrict__ A,
              const __hip_bfloat16* __restrict__ wob,
              const float* __restrict__ bo,
              float* __restrict__ out) {
    __shared__ unsigned short As[2][64 * 32];    // unpadded
    __shared__ unsigned short Bs[2][128 * 32];

    const int tid  = threadIdx.x;
    const int lane = tid & 63;
    const int wv   = tid >> 6;
    const int quad = lane >> 4;
    const int l16  = lane & 15;
    const int wm   = wv >> 1;
    const int wn   = wv & 1;

    const int bid = blockIdx.x;          // 0..511
    const int m0  = (bid >> 3) * 64;
    const int n0  = (bid & 7) * 128;

    const __hip_bfloat16* agl = A   + (size_t)(m0 + wv * 16 + (lane >> 2)) * 1024 + (lane & 3) * 8;
    const __hip_bfloat16* bgl = wob + (size_t)(n0 + wv * 32 + (lane >> 2)) * 1024 + (lane & 3) * 8;

    f32x4 zv = {0.f, 0.f, 0.f, 0.f};
    f32x4 acc[2][4];
#pragma unroll
    for (int ii = 0; ii < 2; ++ii)
#pragma unroll
        for (int jj = 0; jj < 4; ++jj) acc[ii][jj] = zv;

    load16_lds(agl, &As[0][(wv * 16) * 32]);
    load16_lds(bgl, &Bs[0][(wv * 32) * 32]);
    load16_lds(bgl + 16 * 1024, &Bs[0][(wv * 32 + 16) * 32]);
    __syncthreads();

    for (int k0 = 0; k0 < 1024; k0 += 32) {
        const int p = (k0 >> 5) & 1;
        if (k0 + 32 < 1024) {
            const int q = p ^ 1;
            load16_lds(agl + k0 + 32, &As[q][(wv * 16) * 32]);
            load16_lds(bgl + k0 + 32, &Bs[q][(wv * 32) * 32]);
            load16_lds(bgl + 16 * 1024 + k0 + 32, &Bs[q][(wv * 32 + 16) * 32]);
        }
        bf16x8 af[2], bf[4];
#pragma unroll
        for (int ii = 0; ii < 2; ++ii)
            af[ii] = *reinterpret_cast<const bf16x8*>(
                &As[p][(wm * 32 + ii * 16 + l16) * 32 + quad * 8]);
#pragma unroll
        for (int jj = 0; jj < 4; ++jj)
            bf[jj] = *reinterpret_cast<const bf16x8*>(
                &Bs[p][(wn * 64 + jj * 16 + l16) * 32 + quad * 8]);
#pragma unroll
        for (int ii = 0; ii < 2; ++ii)
#pragma unroll
            for (int jj = 0; jj < 4; ++jj)
                acc[ii][jj] = MFMA16(af[ii], bf[jj], acc[ii][jj]);
        __syncthreads();
    }

#pragma unroll
    for (int jj = 0; jj < 4; ++jj) {
        const int n = n0 + wn * 64 + jj * 16 + l16;
        const float bias = bo[n];
#pragma unroll
        for (int ii = 0; ii < 2; ++ii) {
#pragma unroll
            for (int i = 0; i < 4; ++i) {
                const int m = m0 + wm * 32 + ii * 16 + quad * 4 + i;
                out[(size_t)m * 1024 + n] = acc[ii][jj][i] + bias;
            }
        }
    }
}

// ---------------------------------------------------------------------------
extern "C" void kernel_launch(void* const* d_in, const int* in_sizes, int n_in,
                              void* d_out, int out_size, void* d_ws, size_t ws_size,
                              hipStream_t stream) {
    const float* x    = (const float*)d_in[0];
    const float* wqkv = (const float*)d_in[1];
    const float* bqkv = (const float*)d_in[2];
    const float* wo   = (const float*)d_in[3];
    const float* bo   = (const float*)d_in[4];
    float* out = (float*)d_out;

    __hip_bfloat16* ws = (__hip_bfloat16*)d_ws;
    __hip_bfloat16* Q   = ws;                      // [32,2048,64] (x log2e/8)
    __hip_bfloat16* K   = ws + (size_t)4194304;
    __hip_bfloat16* Vt  = ws + (size_t)8388608;
    __hip_bfloat16* AO  = ws + (size_t)12582912;
    __hip_bfloat16* wob = Q;                       // overlay after attn

    // d_out doubles as pre-pass scratch (dead until out_gemm rewrites it):
    __hip_bfloat16* xb     = (__hip_bfloat16*)d_out;            // 4M elems, 8 MB
    __hip_bfloat16* wqkvb  = xb + (size_t)4194304;              // 3M elems, 6 MB

    // 0) merged casts: x (512 blocks) + wqkv (384 blocks)
    cast2_f32_bf16<<<dim3(896), 256, 0, stream>>>(x, xb, wqkv, wqkvb);
    // 1) QKV projection: M=4096, N=3072, K=1024
    qkv_gemm<<<dim3(768), 256, 0, stream>>>(xb, wqkvb, bqkv, Q, K, Vt);
    // 2) attention: 32 bh x 16 q-blocks = 512 blocks, 8 waves, frag-major LDS
    attn_kernel<<<dim3(512), 512, 0, stream>>>(Q, K, Vt, AO);
    // 2b) wo fp32 -> bf16 into dead Q slot (1M elems)
    cast_f32_bf16<<<dim3(128), 256, 0, stream>>>(wo, wob);
    // 3) output projection: M=4096, N=1024, K=1024
    out_gemm<<<dim3(512), 256, 0, stream>>>(AO, wob, bo, out);
}